// Round 10
// baseline (254.774 us; speedup 1.0000x reference)
//
#include <hip/hip_runtime.h>

typedef unsigned short u16;
typedef __bf16 bf16x8 __attribute__((ext_vector_type(8)));
typedef float f32x4 __attribute__((ext_vector_type(4)));
typedef unsigned short u16x4 __attribute__((ext_vector_type(4)));
typedef unsigned short u16x8 __attribute__((ext_vector_type(8)));

#define DIM 1024
#define HEADS 16
#define HD 64
#define SEQ 2048
#define BATCH 4
#define NROWS (BATCH*SEQ)
// raw-logit exp2 constant: 0.125 * log2(e)
#define C2 0.18033688f
// optimistic-softmax overflow trigger (~2^50), applied to lane-local partials
#define THR_PS 1.125899907e15f

__device__ __forceinline__ u16 f2bf(float f) {
  union { float f; unsigned u; } v; v.f = f;
  unsigned r = v.u + 0x7FFFu + ((v.u >> 16) & 1u);   // RNE
  return (u16)(r >> 16);
}

__device__ __forceinline__ unsigned cvt_pk_bf16(float lo, float hi) {
  unsigned r;
  asm("v_cvt_pk_bf16_f32 %0, %1, %2" : "=v"(r) : "v"(lo), "v"(hi));
  return r;
}

__device__ __forceinline__ f32x4 mfma16(bf16x8 a, bf16x8 b, f32x4 c) {
  return __builtin_amdgcn_mfma_f32_16x16x32_bf16(a, b, c, 0, 0, 0);
}

// async global->LDS, 16B per lane; dst must be wave-uniform (HW adds lane*16)
__device__ __forceinline__ void gl_lds16(const void* g, void* l) {
  __builtin_amdgcn_global_load_lds(
      (const __attribute__((address_space(1))) void*)g,
      (__attribute__((address_space(3))) void*)l, 16, 0, 0);
}

// ---------------- cast x (f32 -> bf16), 4 elems/thread ----------------
__global__ __launch_bounds__(256) void cast_f32_bf16(const float* __restrict__ in,
                                                     u16* __restrict__ out) {
  int i = blockIdx.x * 256 + threadIdx.x;
  float4 v = ((const float4*)in)[i];
  u16x4 o = { f2bf(v.x), f2bf(v.y), f2bf(v.z), f2bf(v.w) };
  *(u16x4*)(out + (size_t)i * 4) = o;
}

// ------------- transpose+cast: in[R][C] f32 -> out[C][R] bf16 -------------
__global__ __launch_bounds__(256) void transpose_cast(const float* __restrict__ in,
                                                      u16* __restrict__ out,
                                                      int R, int C) {
  __shared__ u16 tile[64][65];
  int c0 = blockIdx.x * 64, r0 = blockIdx.y * 64;
  int tid = threadIdx.x;
#pragma unroll
  for (int i = 0; i < 16; ++i) {
    int idx = tid + i * 256;
    int r = idx >> 6, c = idx & 63;
    tile[c][r] = f2bf(in[(size_t)(r0 + r) * C + c0 + c]);
  }
  __syncthreads();
#pragma unroll
  for (int i = 0; i < 16; ++i) {
    int idx = tid + i * 256;
    int r = idx >> 6, c = idx & 63;
    out[(size_t)(c0 + r) * R + r0 + c] = tile[r][c];
  }
}

// ---------------- GEMM: C[M,N] = A[M,K] (bf16) @ BT[N,K]^T (bf16) ----------------
// 1D grid + bijective XCD-chunked swizzle (gridDim.x % 8 == 0).
// MODE 1: f32 out + bias (out1 = float*, width N)
// MODE 2: QKV split: cols <2048 -> qk[row][col] (stride 2048) bf16;
//         cols >=2048 (V third) -> vT[(b*16+h)*64+d][pos] with sigma-permutation
//         pos = (seq&~31) | ((seq>>2)&3)<<3 | ((seq>>4)&1)<<2 | (seq&3)
//         (for kv_local = 16a+4g+j -> 8g+4a+j; bit-identical to old transpose_v).
template<int MODE>
__global__ __launch_bounds__(256) void gemm_bt(const u16* __restrict__ A,
                                               const u16* __restrict__ BT,
                                               void* __restrict__ out1,
                                               void* __restrict__ out2,
                                               const float* __restrict__ bias,
                                               int M, int N, int K, int nx) {
  __shared__ __align__(16) u16 As[128 * 64];
  __shared__ __align__(16) u16 Bs[128 * 64];
  const int tid = threadIdx.x;
  const int l = tid & 63, w = tid >> 6, g = l >> 4, ln = l & 15;
  const int cpx = gridDim.x >> 3;
  const int jj = (blockIdx.x & 7) * cpx + (blockIdx.x >> 3);
  const int n0 = (jj % nx) * 128, m0 = (jj / nx) * 128;
  const int wr = w >> 1, wc = w & 1;
  f32x4 acc[4][4];
#pragma unroll
  for (int i = 0; i < 4; ++i)
#pragma unroll
    for (int j = 0; j < 4; ++j) acc[i][j] = (f32x4){0.f, 0.f, 0.f, 0.f};

  const int srow = tid >> 3;
  const int scol = (tid & 7) * 8;
  const u16* Asrc = A  + (size_t)(m0 + srow) * K + scol;
  const u16* Bsrc = BT + (size_t)(n0 + srow) * K + scol;
  char* AsB = (char*)As + (size_t)w * 1024;
  char* BsB = (char*)Bs + (size_t)w * 1024;

  const int nk = K >> 6;
  for (int kt = 0; kt < nk; ++kt) {
    const u16* a0 = Asrc + kt * 64;
    const u16* b0 = Bsrc + kt * 64;
#pragma unroll
    for (int is = 0; is < 4; ++is) {
      gl_lds16(a0 + (size_t)is * 32 * K, AsB + is * 4096);
      gl_lds16(b0 + (size_t)is * 32 * K, BsB + is * 4096);
    }
    __syncthreads();
#pragma unroll
    for (int kk = 0; kk < 2; ++kk) {
      bf16x8 af[4], bfr[4];
#pragma unroll
      for (int i = 0; i < 4; ++i) {
        af[i]  = *(const bf16x8*)(As + (wr * 64 + i * 16 + ln) * 64 + kk * 32 + g * 8);
        bfr[i] = *(const bf16x8*)(Bs + (wc * 64 + i * 16 + ln) * 64 + kk * 32 + g * 8);
      }
#pragma unroll
      for (int mi = 0; mi < 4; ++mi)
#pragma unroll
        for (int ni = 0; ni < 4; ++ni)
          acc[mi][ni] = mfma16(af[mi], bfr[ni], acc[mi][ni]);
    }
    __syncthreads();
  }
#pragma unroll
  for (int mi = 0; mi < 4; ++mi) {
#pragma unroll
    for (int ni = 0; ni < 4; ++ni) {
      int col = n0 + wc * 64 + ni * 16 + ln;
#pragma unroll
      for (int j = 0; j < 4; ++j) {
        int row = m0 + wr * 64 + mi * 16 + g * 4 + j;
        float v = acc[mi][ni][j];
        if (MODE == 1) {
          ((float*)out1)[(size_t)row * N + col] = v + bias[col];
        } else {
          if (col < 2048) {
            ((u16*)out1)[(size_t)row * 2048 + col] = f2bf(v);
          } else {
            int vcol = col - 2048;
            int h2 = vcol >> 6, d2 = vcol & 63;
            int b2 = row >> 11, seq = row & 2047;
            int pos = (seq & ~31) | (((seq >> 2) & 3) << 3)
                    | (((seq >> 4) & 1) << 2) | (seq & 3);
            ((u16*)out2)[((size_t)((b2 << 4) + h2) * 64 + d2) * 2048 + pos] = f2bf(v);
          }
        }
      }
    }
  }
}

// ---------------- flash attention ----------------
// ROUND 10 = round-9 kernel, re-based: Q/K from qk[8192][2048] (stride 2048),
// V from standalone vT (written directly by gemm1's fused epilogue).
// grid 1024 (XCD-chunked); 4 waves; 128 q-rows/block, 32 q-rows/wave (2 Q-frags).
// Double-buffered K/V staging; swapped QK^T; P in registers; V sigma-permuted ->
// PV A-frags single conflict-free b128 reads; optimistic softmax, lane-local lsum
// partials reduced once in epilogue; setprio around MFMA clusters.
__global__ __launch_bounds__(256) void attn_kernel(const u16* __restrict__ qk,
                                                   const u16* __restrict__ vT,
                                                   u16* __restrict__ obuf) {
  __shared__ __align__(16) u16 k_lds[2][64 * 64];
  __shared__ __align__(16) u16 v_lds[2][64 * 64];
  const int wg = blockIdx.x;
  const int j = (wg & 7) * 128 + (wg >> 3);     // 1024 = 8 XCD x 128
  const int qt = j & 15, h = (j >> 4) & 15, b = j >> 8;
  const int tid = threadIdx.x;
  const int w = tid >> 6, l = tid & 63, g = l >> 4, ln = l & 15;
  const int qbase = qt * 128 + w * 32;
  const size_t rs = 2 * DIM;                    // qk row stride

  bf16x8 qf[2][2];
#pragma unroll
  for (int e = 0; e < 2; ++e) {
    const u16* qb = qk + (size_t)(b * SEQ + qbase + e * 16 + ln) * rs + h * HD;
    qf[e][0] = *(const bf16x8*)(qb + g * 8);
    qf[e][1] = *(const bf16x8*)(qb + 32 + g * 8);
  }

  const int krow = tid >> 3;
  const int ksrccol = ((((tid & 7) << 4) ^ ((krow & 7) << 4))) >> 1;  // elements
  const u16* kbase = qk + (size_t)b * SEQ * rs + DIM + h * HD;
  const u16* vtb = vT + (size_t)(b * HEADS + h) * 64 * 2048;
  const int swz = (ln & 7) << 4;

  float m[2] = { -1e30f, -1e30f }, psac[2] = { 0.f, 0.f };  // lane-local partials
  f32x4 of[2][4];
#pragma unroll
  for (int e = 0; e < 2; ++e)
#pragma unroll
    for (int i = 0; i < 4; ++i) of[e][i] = (f32x4){0.f, 0.f, 0.f, 0.f};

  auto stage = [&](int buf, int kv0) {
    const u16* ks0 = kbase + (size_t)(kv0 + krow) * rs + ksrccol;
    const u16* vs0 = vtb + (size_t)krow * 2048 + kv0 + ksrccol;
    char* kd = (char*)(&k_lds[buf][0]) + (size_t)w * 1024;
    char* vd = (char*)(&v_lds[buf][0]) + (size_t)w * 1024;
    gl_lds16(ks0, kd);
    gl_lds16(ks0 + (size_t)32 * rs, kd + 4096);
    gl_lds16(vs0, vd);
    gl_lds16(vs0 + (size_t)32 * 2048, vd + 4096);
  };

  stage(0, 0);
  __syncthreads();
  int cur = 0;

  for (int t = 0; t < 32; ++t) {
    if (t < 31) stage(cur ^ 1, (t + 1) * 64);    // prefetch hides under compute

    // ---- S^T = K @ Q^T (raw logits), K frags reused across both Q frags ----
    f32x4 sacc[2][4];
#pragma unroll
    for (int e = 0; e < 2; ++e)
#pragma unroll
      for (int f = 0; f < 4; ++f) sacc[e][f] = (f32x4){0.f, 0.f, 0.f, 0.f};
    __builtin_amdgcn_s_setprio(1);
#pragma unroll
    for (int f = 0; f < 4; ++f) {
      const char* kr = (const char*)(&k_lds[cur][0]) + (f * 16 + ln) * 128;
      bf16x8 a0 = *(const bf16x8*)(kr + ((g * 16) ^ swz));
      bf16x8 a1 = *(const bf16x8*)(kr + ((64 | (g * 16)) ^ swz));
#pragma unroll
      for (int e = 0; e < 2; ++e) {
        sacc[e][f] = mfma16(a0, qf[e][0], sacc[e][f]);
        sacc[e][f] = mfma16(a1, qf[e][1], sacc[e][f]);
      }
    }
    __builtin_amdgcn_s_setprio(0);

    // ---- optimistic softmax: p = exp2(fma(s, C2, -m*C2)); lane-local partials ----
    union pu { unsigned wd[4]; bf16x8 bv; } pf[2][2];
    float ps[2];
#pragma unroll
    for (int e = 0; e < 2; ++e) {
      const float mc = m[e] * C2;
      float s2 = 0.f;
#pragma unroll
      for (int f = 0; f < 4; ++f)
#pragma unroll
        for (int j2 = 0; j2 < 2; ++j2) {
          float p0 = __builtin_amdgcn_exp2f(fmaf(sacc[e][f][2 * j2], C2, -mc));
          float p1 = __builtin_amdgcn_exp2f(fmaf(sacc[e][f][2 * j2 + 1], C2, -mc));
          s2 += p0 + p1;
          pf[e][f >> 1].wd[(f & 1) * 2 + j2] = cvt_pk_bf16(p0, p1);
        }
      ps[e] = s2;
    }
    if (__any(fmaxf(ps[0], ps[1]) > THR_PS)) {   // rare: tile 0 + pathological growth
#pragma unroll
      for (int e = 0; e < 2; ++e) {
        float tm = -3e38f;
#pragma unroll
        for (int f = 0; f < 4; ++f)
#pragma unroll
          for (int jj = 0; jj < 4; ++jj) tm = fmaxf(tm, sacc[e][f][jj]);
        tm = fmaxf(tm, __shfl_xor(tm, 16));
        tm = fmaxf(tm, __shfl_xor(tm, 32));
        float mn = fmaxf(m[e], tm);
        float rc = __builtin_amdgcn_exp2f((m[e] - mn) * C2);
        psac[e] *= rc;
#pragma unroll
        for (int fd = 0; fd < 4; ++fd) of[e][fd] *= rc;
        m[e] = mn;
        const float mc = mn * C2;
        float s2 = 0.f;
#pragma unroll
        for (int f = 0; f < 4; ++f)
#pragma unroll
          for (int j2 = 0; j2 < 2; ++j2) {
            float p0 = __builtin_amdgcn_exp2f(fmaf(sacc[e][f][2 * j2], C2, -mc));
            float p1 = __builtin_amdgcn_exp2f(fmaf(sacc[e][f][2 * j2 + 1], C2, -mc));
            s2 += p0 + p1;
            pf[e][f >> 1].wd[(f & 1) * 2 + j2] = cvt_pk_bf16(p0, p1);
          }
        ps[e] = s2;
      }
    }
    psac[0] += ps[0];
    psac[1] += ps[1];

    // ---- PV: O^T += V^T @ P^T; single b128 A-frag per (kk,fd), reused over e ----
    __builtin_amdgcn_s_setprio(1);
#pragma unroll
    for (int kk = 0; kk < 2; ++kk)
#pragma unroll
      for (int fd = 0; fd < 4; ++fd) {
        const char* vr = (const char*)(&v_lds[cur][0]) + (fd * 16 + ln) * 128;
        bf16x8 fa = *(const bf16x8*)(vr + ((kk * 64 + g * 16) ^ swz));
#pragma unroll
        for (int e = 0; e < 2; ++e)
          of[e][fd] = mfma16(fa, pf[e][kk].bv, of[e][fd]);
      }
    __builtin_amdgcn_s_setprio(0);

    __syncthreads();   // drains this wave's prefetch (vmcnt) + guards buf reuse
    cur ^= 1;
  }

  // epilogue: reduce lsum once; o[q][d] = O^T[d][q] / lsum[q]; d = fd*16 + 4g + j
#pragma unroll
  for (int e = 0; e < 2; ++e) {
    float ls = psac[e];
    ls += __shfl_xor(ls, 16);
    ls += __shfl_xor(ls, 32);
    float linv = 1.f / ls;
    u16* orow = obuf + (size_t)(b * SEQ + qbase + e * 16 + ln) * DIM + h * HD;
#pragma unroll
    for (int fd = 0; fd < 4; ++fd) {
      unsigned w0 = cvt_pk_bf16(of[e][fd][0] * linv, of[e][fd][1] * linv);
      unsigned w1 = cvt_pk_bf16(of[e][fd][2] * linv, of[e][fd][3] * linv);
      unsigned* dst = (unsigned*)(orow + fd * 16 + g * 4);
      dst[0] = w0;
      dst[1] = w1;
    }
  }
}

extern "C" void kernel_launch(void* const* d_in, const int* in_sizes, int n_in,
                              void* d_out, int out_size, void* d_ws, size_t ws_size,
                              hipStream_t stream) {
  const float* x     = (const float*)d_in[0];
  const float* w_in  = (const float*)d_in[1];
  const float* w_out = (const float*)d_in[2];
  const float* b_out = (const float*)d_in[3];
  float* out = (float*)d_out;

  char* ws = (char*)d_ws;
  u16* xb     = (u16*)(ws);                               // 16 MiB: x bf16
  u16* w_inT  = (u16*)(ws + (size_t)16 * 1024 * 1024);    //  6 MiB: [3072][1024]
  u16* w_outT = (u16*)(ws + (size_t)22 * 1024 * 1024);    //  2 MiB: [1024][1024]
  u16* qk     = (u16*)(ws + (size_t)24 * 1024 * 1024);    // 32 MiB: [8192][2048] (Q|K)
  u16* vT     = (u16*)(ws + (size_t)56 * 1024 * 1024);    // 16 MiB: [1024][2048] (sigma-permuted)
  u16* obuf   = (u16*)(ws + (size_t)72 * 1024 * 1024);    // 16 MiB: [8192][1024]

  cast_f32_bf16<<<8192, 256, 0, stream>>>(x, xb);
  transpose_cast<<<dim3(48, 16), 256, 0, stream>>>(w_in, w_inT, 1024, 3072);
  transpose_cast<<<dim3(16, 16), 256, 0, stream>>>(w_out, w_outT, 1024, 1024);
  // qkv projection: Q,K -> qk; V -> vT (fused transpose + sigma-permutation)
  gemm_bt<2><<<1536, 256, 0, stream>>>(xb, w_inT, qk, vT, nullptr, NROWS, 3 * DIM, DIM, 24);
  attn_kernel<<<1024, 256, 0, stream>>>(qk, vT, obuf);
  gemm_bt<1><<<512, 256, 0, stream>>>(obuf, w_outT, out, nullptr, b_out, NROWS, DIM, DIM, 8);
}

// Round 12
// 231.885 us; speedup vs baseline: 1.0987x; 1.0987x over previous
//
#include <hip/hip_runtime.h>

typedef unsigned short u16;
typedef __bf16 bf16x8 __attribute__((ext_vector_type(8)));
typedef float f32x4 __attribute__((ext_vector_type(4)));
typedef unsigned short u16x4 __attribute__((ext_vector_type(4)));
typedef unsigned short u16x8 __attribute__((ext_vector_type(8)));

#define DIM 1024
#define HEADS 16
#define HD 64
#define SEQ 2048
#define BATCH 4
#define NROWS (BATCH*SEQ)
// raw-logit exp2 constant: 0.125 * log2(e)
#define C2 0.18033688f
// optimistic-softmax overflow trigger (~2^50), applied to lane-local partials
#define THR_PS 1.125899907e15f

__device__ __forceinline__ u16 f2bf(float f) {
  union { float f; unsigned u; } v; v.f = f;
  unsigned r = v.u + 0x7FFFu + ((v.u >> 16) & 1u);   // RNE
  return (u16)(r >> 16);
}

__device__ __forceinline__ unsigned cvt_pk_bf16(float lo, float hi) {
  unsigned r;
  asm("v_cvt_pk_bf16_f32 %0, %1, %2" : "=v"(r) : "v"(lo), "v"(hi));
  return r;
}

__device__ __forceinline__ f32x4 mfma16(bf16x8 a, bf16x8 b, f32x4 c) {
  return __builtin_amdgcn_mfma_f32_16x16x32_bf16(a, b, c, 0, 0, 0);
}

// async global->LDS, 16B per lane; dst must be wave-uniform (HW adds lane*16)
__device__ __forceinline__ void gl_lds16(const void* g, void* l) {
  __builtin_amdgcn_global_load_lds(
      (const __attribute__((address_space(1))) void*)g,
      (__attribute__((address_space(3))) void*)l, 16, 0, 0);
}

// ---------------- merged preprocessing ----------------
// blocks [0,8192): cast x f32->bf16 (4 elems/thread)
// blocks [8192,8960): transpose+cast w_in  [1024][3072] -> w_inT  [3072][1024]
// blocks [8960,9216): transpose+cast w_out [1024][1024] -> w_outT [1024][1024]
__global__ __launch_bounds__(256) void prep_kernel(const float* __restrict__ x,
                                                   const float* __restrict__ w_in,
                                                   const float* __restrict__ w_out,
                                                   u16* __restrict__ xb,
                                                   u16* __restrict__ w_inT,
                                                   u16* __restrict__ w_outT) {
  __shared__ u16 tile[64][65];
  const int bid = blockIdx.x;
  const int tid = threadIdx.x;
  if (bid < 8192) {
    int i = bid * 256 + tid;
    float4 v = ((const float4*)x)[i];
    u16x4 o = { f2bf(v.x), f2bf(v.y), f2bf(v.z), f2bf(v.w) };
    *(u16x4*)(xb + (size_t)i * 4) = o;
    return;
  }
  const float* in;
  u16* out;
  int R, C, c0, r0;
  if (bid < 8960) {
    int b2 = bid - 8192;             // 768 = 48 x 16
    in = w_in; out = w_inT; R = 1024; C = 3072;
    c0 = (b2 % 48) * 64; r0 = (b2 / 48) * 64;
  } else {
    int b3 = bid - 8960;             // 256 = 16 x 16
    in = w_out; out = w_outT; R = 1024; C = 1024;
    c0 = (b3 % 16) * 64; r0 = (b3 / 16) * 64;
  }
#pragma unroll
  for (int i = 0; i < 16; ++i) {
    int idx = tid + i * 256;
    int r = idx >> 6, c = idx & 63;
    tile[c][r] = f2bf(in[(size_t)(r0 + r) * C + c0 + c]);
  }
  __syncthreads();
#pragma unroll
  for (int i = 0; i < 16; ++i) {
    int idx = tid + i * 256;
    int r = idx >> 6, c = idx & 63;
    out[(size_t)(c0 + r) * R + r0 + c] = tile[r][c];
  }
}

// ------------- V pre-transpose (kv sigma-permuted within 32-blocks) -------------
// vT[bh][d][pos]: for kv_local = 16a + 4g + j (within 32-block), pos = 8g + 4a + j.
// u32 (kv-pair) level: x = kv2 in 0..15 -> ((x&6)<<1) | ((x&8)>>2) | (x&1).
__global__ __launch_bounds__(256) void transpose_v(const u16* __restrict__ qkv,
                                                   u16* __restrict__ vT) {
  __shared__ unsigned t32[64][37];
  const int t = blockIdx.x, bh = blockIdx.y;
  const int b = bh >> 4, h = bh & 15;
  const u16* src = qkv + ((size_t)(b * SEQ + t * 64)) * 3072 + 2048 + h * 64;
  const int tid = threadIdx.x;
#pragma unroll
  for (int i = 0; i < 8; ++i) {
    int lin = tid + i * 256;
    int r2 = lin >> 6, c = lin & 63;
    unsigned lo = src[(size_t)(2 * r2) * 3072 + c];
    unsigned hi = src[(size_t)(2 * r2 + 1) * 3072 + c];
    t32[c][r2] = lo | (hi << 16);
  }
  __syncthreads();
  unsigned* dst = (unsigned*)(vT + (size_t)bh * 64 * 2048);
#pragma unroll
  for (int i = 0; i < 8; ++i) {
    int lin = tid + i * 256;
    int d = lin >> 5, r2 = lin & 31;
    int rp = (r2 & 16) | ((r2 & 6) << 1) | ((r2 & 8) >> 2) | (r2 & 1);
    dst[(size_t)d * 1024 + t * 32 + rp] = t32[d][r2];
  }
}

// ---------------- GEMM: C[M,N] = A[M,K] (bf16) @ BT[N,K]^T (bf16) ----------------
// 1D grid + bijective XCD-chunked swizzle (gridDim.x % 8 == 0).
template<int OUT_F32>
__global__ __launch_bounds__(256) void gemm_bt(const u16* __restrict__ A,
                                               const u16* __restrict__ BT,
                                               void* __restrict__ Cout,
                                               const float* __restrict__ bias,
                                               int M, int N, int K, int nx) {
  __shared__ __align__(16) u16 As[128 * 64];
  __shared__ __align__(16) u16 Bs[128 * 64];
  const int tid = threadIdx.x;
  const int l = tid & 63, w = tid >> 6, g = l >> 4, ln = l & 15;
  const int cpx = gridDim.x >> 3;
  const int jj = (blockIdx.x & 7) * cpx + (blockIdx.x >> 3);
  const int n0 = (jj % nx) * 128, m0 = (jj / nx) * 128;
  const int wr = w >> 1, wc = w & 1;
  f32x4 acc[4][4];
#pragma unroll
  for (int i = 0; i < 4; ++i)
#pragma unroll
    for (int j = 0; j < 4; ++j) acc[i][j] = (f32x4){0.f, 0.f, 0.f, 0.f};

  const int srow = tid >> 3;
  const int scol = (tid & 7) * 8;
  const u16* Asrc = A  + (size_t)(m0 + srow) * K + scol;
  const u16* Bsrc = BT + (size_t)(n0 + srow) * K + scol;
  char* AsB = (char*)As + (size_t)w * 1024;
  char* BsB = (char*)Bs + (size_t)w * 1024;

  const int nk = K >> 6;
  for (int kt = 0; kt < nk; ++kt) {
    const u16* a0 = Asrc + kt * 64;
    const u16* b0 = Bsrc + kt * 64;
#pragma unroll
    for (int is = 0; is < 4; ++is) {
      gl_lds16(a0 + (size_t)is * 32 * K, AsB + is * 4096);
      gl_lds16(b0 + (size_t)is * 32 * K, BsB + is * 4096);
    }
    __syncthreads();
#pragma unroll
    for (int kk = 0; kk < 2; ++kk) {
      bf16x8 af[4], bfr[4];
#pragma unroll
      for (int i = 0; i < 4; ++i) {
        af[i]  = *(const bf16x8*)(As + (wr * 64 + i * 16 + ln) * 64 + kk * 32 + g * 8);
        bfr[i] = *(const bf16x8*)(Bs + (wc * 64 + i * 16 + ln) * 64 + kk * 32 + g * 8);
      }
#pragma unroll
      for (int mi = 0; mi < 4; ++mi)
#pragma unroll
        for (int ni = 0; ni < 4; ++ni)
          acc[mi][ni] = mfma16(af[mi], bfr[ni], acc[mi][ni]);
    }
    __syncthreads();
  }
#pragma unroll
  for (int mi = 0; mi < 4; ++mi) {
#pragma unroll
    for (int ni = 0; ni < 4; ++ni) {
      int col = n0 + wc * 64 + ni * 16 + ln;
#pragma unroll
      for (int j = 0; j < 4; ++j) {
        int row = m0 + wr * 64 + mi * 16 + g * 4 + j;
        float v = acc[mi][ni][j];
        if (OUT_F32) {
          ((float*)Cout)[(size_t)row * N + col] = v + bias[col];
        } else {
          ((u16*)Cout)[(size_t)row * N + col] = f2bf(v);
        }
      }
    }
  }
}

// ---------------- flash attention (round-9 form, proven) ----------------
// grid 1024 (XCD-chunked); 4 waves; 128 q-rows/block, 32 q-rows/wave (2 Q-frags).
// Double-buffered K/V staging; swapped QK^T; P in registers; V sigma-permuted ->
// PV A-frags single conflict-free b128 reads; optimistic softmax, lane-local lsum
// partials reduced once in epilogue; setprio around MFMA clusters.
__global__ __launch_bounds__(256) void attn_kernel(const u16* __restrict__ qkv,
                                                   const u16* __restrict__ vT,
                                                   u16* __restrict__ obuf) {
  __shared__ __align__(16) u16 k_lds[2][64 * 64];
  __shared__ __align__(16) u16 v_lds[2][64 * 64];
  const int wg = blockIdx.x;
  const int j = (wg & 7) * 128 + (wg >> 3);     // 1024 = 8 XCD x 128
  const int qt = j & 15, h = (j >> 4) & 15, b = j >> 8;
  const int tid = threadIdx.x;
  const int w = tid >> 6, l = tid & 63, g = l >> 4, ln = l & 15;
  const int qbase = qt * 128 + w * 32;
  const size_t rs = 3 * DIM;

  bf16x8 qf[2][2];
#pragma unroll
  for (int e = 0; e < 2; ++e) {
    const u16* qb = qkv + (size_t)(b * SEQ + qbase + e * 16 + ln) * rs + h * HD;
    qf[e][0] = *(const bf16x8*)(qb + g * 8);
    qf[e][1] = *(const bf16x8*)(qb + 32 + g * 8);
  }

  const int krow = tid >> 3;
  const int ksrccol = ((((tid & 7) << 4) ^ ((krow & 7) << 4))) >> 1;  // elements
  const u16* kbase = qkv + (size_t)b * SEQ * rs + DIM + h * HD;
  const u16* vtb = vT + (size_t)(b * HEADS + h) * 64 * 2048;
  const int swz = (ln & 7) << 4;

  float m[2] = { -1e30f, -1e30f }, psac[2] = { 0.f, 0.f };  // lane-local partials
  f32x4 of[2][4];
#pragma unroll
  for (int e = 0; e < 2; ++e)
#pragma unroll
    for (int i = 0; i < 4; ++i) of[e][i] = (f32x4){0.f, 0.f, 0.f, 0.f};

  auto stage = [&](int buf, int kv0) {
    const u16* ks0 = kbase + (size_t)(kv0 + krow) * rs + ksrccol;
    const u16* vs0 = vtb + (size_t)krow * 2048 + kv0 + ksrccol;
    char* kd = (char*)(&k_lds[buf][0]) + (size_t)w * 1024;
    char* vd = (char*)(&v_lds[buf][0]) + (size_t)w * 1024;
    gl_lds16(ks0, kd);
    gl_lds16(ks0 + (size_t)32 * rs, kd + 4096);
    gl_lds16(vs0, vd);
    gl_lds16(vs0 + (size_t)32 * 2048, vd + 4096);
  };

  stage(0, 0);
  __syncthreads();
  int cur = 0;

  for (int t = 0; t < 32; ++t) {
    if (t < 31) stage(cur ^ 1, (t + 1) * 64);    // prefetch hides under compute

    // ---- S^T = K @ Q^T (raw logits), K frags reused across both Q frags ----
    f32x4 sacc[2][4];
#pragma unroll
    for (int e = 0; e < 2; ++e)
#pragma unroll
      for (int f = 0; f < 4; ++f) sacc[e][f] = (f32x4){0.f, 0.f, 0.f, 0.f};
    __builtin_amdgcn_s_setprio(1);
#pragma unroll
    for (int f = 0; f < 4; ++f) {
      const char* kr = (const char*)(&k_lds[cur][0]) + (f * 16 + ln) * 128;
      bf16x8 a0 = *(const bf16x8*)(kr + ((g * 16) ^ swz));
      bf16x8 a1 = *(const bf16x8*)(kr + ((64 | (g * 16)) ^ swz));
#pragma unroll
      for (int e = 0; e < 2; ++e) {
        sacc[e][f] = mfma16(a0, qf[e][0], sacc[e][f]);
        sacc[e][f] = mfma16(a1, qf[e][1], sacc[e][f]);
      }
    }
    __builtin_amdgcn_s_setprio(0);

    // ---- optimistic softmax: p = exp2(fma(s, C2, -m*C2)); lane-local partials ----
    union pu { unsigned wd[4]; bf16x8 bv; } pf[2][2];
    float ps[2];
#pragma unroll
    for (int e = 0; e < 2; ++e) {
      const float mc = m[e] * C2;
      float s2 = 0.f;
#pragma unroll
      for (int f = 0; f < 4; ++f)
#pragma unroll
        for (int j2 = 0; j2 < 2; ++j2) {
          float p0 = __builtin_amdgcn_exp2f(fmaf(sacc[e][f][2 * j2], C2, -mc));
          float p1 = __builtin_amdgcn_exp2f(fmaf(sacc[e][f][2 * j2 + 1], C2, -mc));
          s2 += p0 + p1;
          pf[e][f >> 1].wd[(f & 1) * 2 + j2] = cvt_pk_bf16(p0, p1);
        }
      ps[e] = s2;
    }
    if (__any(fmaxf(ps[0], ps[1]) > THR_PS)) {   // rare: tile 0 + pathological growth
#pragma unroll
      for (int e = 0; e < 2; ++e) {
        float tm = -3e38f;
#pragma unroll
        for (int f = 0; f < 4; ++f)
#pragma unroll
          for (int jj = 0; jj < 4; ++jj) tm = fmaxf(tm, sacc[e][f][jj]);
        tm = fmaxf(tm, __shfl_xor(tm, 16));
        tm = fmaxf(tm, __shfl_xor(tm, 32));
        float mn = fmaxf(m[e], tm);
        float rc = __builtin_amdgcn_exp2f((m[e] - mn) * C2);
        psac[e] *= rc;
#pragma unroll
        for (int fd = 0; fd < 4; ++fd) of[e][fd] *= rc;
        m[e] = mn;
        const float mc = mn * C2;
        float s2 = 0.f;
#pragma unroll
        for (int f = 0; f < 4; ++f)
#pragma unroll
          for (int j2 = 0; j2 < 2; ++j2) {
            float p0 = __builtin_amdgcn_exp2f(fmaf(sacc[e][f][2 * j2], C2, -mc));
            float p1 = __builtin_amdgcn_exp2f(fmaf(sacc[e][f][2 * j2 + 1], C2, -mc));
            s2 += p0 + p1;
            pf[e][f >> 1].wd[(f & 1) * 2 + j2] = cvt_pk_bf16(p0, p1);
          }
        ps[e] = s2;
      }
    }
    psac[0] += ps[0];
    psac[1] += ps[1];

    // ---- PV: O^T += V^T @ P^T; single b128 A-frag per (kk,fd), reused over e ----
    __builtin_amdgcn_s_setprio(1);
#pragma unroll
    for (int kk = 0; kk < 2; ++kk)
#pragma unroll
      for (int fd = 0; fd < 4; ++fd) {
        const char* vr = (const char*)(&v_lds[cur][0]) + (fd * 16 + ln) * 128;
        bf16x8 fa = *(const bf16x8*)(vr + ((kk * 64 + g * 16) ^ swz));
#pragma unroll
        for (int e = 0; e < 2; ++e)
          of[e][fd] = mfma16(fa, pf[e][kk].bv, of[e][fd]);
      }
    __builtin_amdgcn_s_setprio(0);

    __syncthreads();   // drains this wave's prefetch (vmcnt) + guards buf reuse
    cur ^= 1;
  }

  // epilogue: reduce lsum once; o[q][d] = O^T[d][q] / lsum[q]; d = fd*16 + 4g + j
#pragma unroll
  for (int e = 0; e < 2; ++e) {
    float ls = psac[e];
    ls += __shfl_xor(ls, 16);
    ls += __shfl_xor(ls, 32);
    float linv = 1.f / ls;
    u16* orow = obuf + (size_t)(b * SEQ + qbase + e * 16 + ln) * DIM + h * HD;
#pragma unroll
    for (int fd = 0; fd < 4; ++fd) {
      unsigned w0 = cvt_pk_bf16(of[e][fd][0] * linv, of[e][fd][1] * linv);
      unsigned w1 = cvt_pk_bf16(of[e][fd][2] * linv, of[e][fd][3] * linv);
      unsigned* dst = (unsigned*)(orow + fd * 16 + g * 4);
      dst[0] = w0;
      dst[1] = w1;
    }
  }
}

extern "C" void kernel_launch(void* const* d_in, const int* in_sizes, int n_in,
                              void* d_out, int out_size, void* d_ws, size_t ws_size,
                              hipStream_t stream) {
  const float* x     = (const float*)d_in[0];
  const float* w_in  = (const float*)d_in[1];
  const float* w_out = (const float*)d_in[2];
  const float* b_out = (const float*)d_in[3];
  float* out = (float*)d_out;

  char* ws = (char*)d_ws;
  u16* xb     = (u16*)(ws);                               // 16 MiB: x bf16 (dead after gemm1)
  u16* vT     = (u16*)(ws);                               // 16 MiB: aliases xb
  u16* w_inT  = (u16*)(ws + (size_t)16 * 1024 * 1024);    //  6 MiB
  u16* w_outT = (u16*)(ws + (size_t)22 * 1024 * 1024);    //  2 MiB
  u16* qkv    = (u16*)(ws + (size_t)24 * 1024 * 1024);    // 48 MiB
  u16* obuf   = (u16*)(ws + (size_t)72 * 1024 * 1024);    // 16 MiB

  prep_kernel<<<9216, 256, 0, stream>>>(x, w_in, w_out, xb, w_inT, w_outT);
  gemm_bt<0><<<1536, 256, 0, stream>>>(xb, w_inT, qkv, nullptr, NROWS, 3 * DIM, DIM, 24);
  transpose_v<<<dim3(32, 64), 256, 0, stream>>>(qkv, vT);
  attn_kernel<<<1024, 256, 0, stream>>>(qkv, vT, obuf);
  gemm_bt<1><<<512, 256, 0, stream>>>(obuf, w_outT, out, b_out, NROWS, DIM, DIM, 8);
}